// Round 4
// baseline (372.417 us; speedup 1.0000x reference)
//
#include <hip/hip_runtime.h>

// MQA forward. Reference dtypes: ALL float32 (inputs and output).
// Pipeline: [f32->bf16 convert] -> [qkv GEMM (Q, K, V^T)] -> [flash attn] -> [out GEMM -> f32].
// Compute in bf16 MFMA with fp32 accumulation. HIDDEN=2048, HEADS=16, HEAD_DIM=128, M=4096.

using bf16   = __bf16;
using bf16x4 = __bf16 __attribute__((ext_vector_type(4)));
using bf16x8 = __bf16 __attribute__((ext_vector_type(8)));
using f32x4  = float  __attribute__((ext_vector_type(4)));

// ---------------------------------------------------------------------------
// f32 -> bf16 conversion, 8 elems/thread, n multiple of 2048
// ---------------------------------------------------------------------------
__global__ __launch_bounds__(256) void cvt_kernel(
    const float* __restrict__ src, bf16* __restrict__ dst)
{
    const int i = (blockIdx.x * 256 + threadIdx.x) * 8;
    float4 f0 = *(const float4*)(src + i);
    float4 f1 = *(const float4*)(src + i + 4);
    bf16x8 v;
    v[0] = (bf16)f0.x; v[1] = (bf16)f0.y; v[2] = (bf16)f0.z; v[3] = (bf16)f0.w;
    v[4] = (bf16)f1.x; v[5] = (bf16)f1.y; v[6] = (bf16)f1.z; v[7] = (bf16)f1.w;
    *(bf16x8*)(dst + i) = v;
}

// ---------------------------------------------------------------------------
// 128x128-tile NT GEMM core: C[M][N] = A[M][2048] * B[N][2048]^T, bf16 inputs.
// m93 structure: BK=32, register staging + ds_write_b128, 16 MFMA / K-step.
// mode: 0 = bf16 C, 1 = bf16 C transposed (C[n][m]), 2 = f32 C.
// ---------------------------------------------------------------------------
__device__ __forceinline__ void gemm128(
    const bf16* __restrict__ A, const bf16* __restrict__ B, void* __restrict__ Cp,
    int bm, int bn, int ldC, int mode)
{
    __shared__ bf16 As[128 * 32];
    __shared__ bf16 Bs[128 * 32];
    const int K = 2048;

    const int tid  = threadIdx.x;
    const int wave = tid >> 6;
    const int lane = tid & 63;
    const int quad = lane >> 4;
    const int c    = lane & 15;
    const int wm   = (wave >> 1) << 6;   // wave's 64x64 subtile
    const int wn   = (wave & 1) << 6;

    // staging map: thread -> (row = tid/4, col8 = (tid%4)*8)
    const int srow = tid >> 2;
    const int scol = (tid & 3) << 3;
    const bf16* Ag = A + (size_t)(bm + srow) * K + scol;
    const bf16* Bg = B + (size_t)(bn + srow) * K + scol;

    f32x4 acc[4][4];
#pragma unroll
    for (int i = 0; i < 4; ++i)
#pragma unroll
        for (int j = 0; j < 4; ++j)
            acc[i][j] = f32x4{0.f, 0.f, 0.f, 0.f};

    for (int k0 = 0; k0 < K; k0 += 32) {
        bf16x8 a0 = *(const bf16x8*)(Ag + k0);
        bf16x8 a1 = *(const bf16x8*)(Ag + k0 + 64 * K);
        bf16x8 b0 = *(const bf16x8*)(Bg + k0);
        bf16x8 b1 = *(const bf16x8*)(Bg + k0 + 64 * K);

        __syncthreads();                 // prev iter's frag reads done
        *(bf16x8*)(As + (srow)      * 32 + scol) = a0;
        *(bf16x8*)(As + (64 + srow) * 32 + scol) = a1;
        *(bf16x8*)(Bs + (srow)      * 32 + scol) = b0;
        *(bf16x8*)(Bs + (64 + srow) * 32 + scol) = b1;
        __syncthreads();                 // staging visible

        bf16x8 af[4], bfv[4];
#pragma unroll
        for (int i = 0; i < 4; ++i)
            af[i] = *(const bf16x8*)(As + (wm + i * 16 + c) * 32 + quad * 8);
#pragma unroll
        for (int j = 0; j < 4; ++j)
            bfv[j] = *(const bf16x8*)(Bs + (wn + j * 16 + c) * 32 + quad * 8);
#pragma unroll
        for (int i = 0; i < 4; ++i)
#pragma unroll
            for (int j = 0; j < 4; ++j)
                acc[i][j] = __builtin_amdgcn_mfma_f32_16x16x32_bf16(af[i], bfv[j], acc[i][j], 0, 0, 0);
    }

    // C/D layout: col = lane&15, row = quad*4 + reg
    if (mode == 0) {
        bf16* C = (bf16*)Cp;
#pragma unroll
        for (int i = 0; i < 4; ++i) {
            const int m = bm + wm + i * 16 + quad * 4;
#pragma unroll
            for (int j = 0; j < 4; ++j) {
                const int n = bn + wn + j * 16 + c;
#pragma unroll
                for (int r = 0; r < 4; ++r)
                    C[(size_t)(m + r) * ldC + n] = (bf16)acc[i][j][r];
            }
        }
    } else if (mode == 1) {
        // transposed store: 4 consecutive regs = 4 consecutive m -> 8B packed store
        bf16* C = (bf16*)Cp;
#pragma unroll
        for (int j = 0; j < 4; ++j) {
            const int n = bn + wn + j * 16 + c;
#pragma unroll
            for (int i = 0; i < 4; ++i) {
                const int m = bm + wm + i * 16 + quad * 4;
                bf16x4 v;
#pragma unroll
                for (int r = 0; r < 4; ++r) v[r] = (bf16)acc[i][j][r];
                *(bf16x4*)(C + (size_t)n * ldC + m) = v;
            }
        }
    } else {
        float* C = (float*)Cp;
#pragma unroll
        for (int i = 0; i < 4; ++i) {
            const int m = bm + wm + i * 16 + quad * 4;
#pragma unroll
            for (int j = 0; j < 4; ++j) {
                const int n = bn + wn + j * 16 + c;
#pragma unroll
                for (int r = 0; r < 4; ++r)
                    C[(size_t)(m + r) * ldC + n] = acc[i][j][r];
            }
        }
    }
}

// bx 0..15: Q = x @ w_q^T (cols bx*128); bx==16: K = x @ w_k^T; bx==17: V^T (transposed)
__global__ __launch_bounds__(256) void qkv_kernel(
    const bf16* __restrict__ x,  const bf16* __restrict__ wq,
    const bf16* __restrict__ wk, const bf16* __restrict__ wv,
    bf16* __restrict__ Qb, bf16* __restrict__ Kb, bf16* __restrict__ Vt)
{
    const int bx = blockIdx.x;
    const int bm = blockIdx.y << 7;
    const bf16* B; bf16* C; int ldC, bn, mode;
    if (bx < 16)       { B = wq; C = Qb; ldC = 2048; bn = bx << 7; mode = 0; }
    else if (bx == 16) { B = wk; C = Kb; ldC = 128;  bn = 0;       mode = 0; }
    else               { B = wv; C = Vt; ldC = 4096; bn = 0;       mode = 1; }
    gemm128(x, B, C, bm, bn, ldC, mode);
}

__global__ __launch_bounds__(256) void out_kernel(
    const bf16* __restrict__ AO, const bf16* __restrict__ wo, float* __restrict__ out)
{
    gemm128(AO, wo, out, blockIdx.y << 7, blockIdx.x << 7, 2048, 2);
}

// ---------------------------------------------------------------------------
// Flash attention: one block per (q-tile 128, head, batch). t-tile = 64.
// Register staging into PADDED LDS, full barriers.
// Wave w owns query rows w*32..w*32+31 (softmax stats intra-quad shuffles only).
// AO may alias Qb: each block reads only its own (rows, head-slice) of Q at
// kernel start and writes exactly that slice of AO at kernel end.
// ---------------------------------------------------------------------------
#define KS_LD 136   // 128 + 8 pad
#define VS_LD 72    // 64 + 8 pad
#define PS_LD 72    // 64 + 8 pad

__global__ __launch_bounds__(256, 2) void attn_kernel(
    const bf16* __restrict__ Qb, const bf16* __restrict__ Kb,
    const bf16* __restrict__ Vt, bf16* __restrict__ AO)
{
    __shared__ bf16 Ks[64 * KS_LD];   // [t][d]
    __shared__ bf16 Vs[128 * VS_LD];  // [d][t]
    __shared__ bf16 Ps[128 * PS_LD];  // [qrow][t]

    const float kScale = 0.08838834764831845f;  // 1/sqrt(128)
    const int tid  = threadIdx.x;
    const int lane = tid & 63;
    const int wave = tid >> 6;
    const int quad = lane >> 4;
    const int c    = lane & 15;
    const int qt = blockIdx.x, h = blockIdx.y, b = blockIdx.z;
    const int rowbase = b * 2048 + qt * 128;
    const int wrow = wave * 32;

    // Q fragments: rows wrow+i*16+c, d = ks*32 + quad*8 (A-operand layout)
    bf16x8 qf[2][4];
#pragma unroll
    for (int i = 0; i < 2; ++i)
#pragma unroll
        for (int ks = 0; ks < 4; ++ks)
            qf[i][ks] = *(const bf16x8*)(Qb + (size_t)(rowbase + wrow + i * 16 + c) * 2048
                                            + h * 128 + ks * 32 + quad * 8);

    f32x4 o[2][8];
#pragma unroll
    for (int i = 0; i < 2; ++i)
#pragma unroll
        for (int jd = 0; jd < 8; ++jd) o[i][jd] = f32x4{0.f, 0.f, 0.f, 0.f};

    float m_run[2][4], l_run[2][4];   // slot (i,r) -> row wrow+i*16+quad*4+r (quad-replicated)
#pragma unroll
    for (int i = 0; i < 2; ++i)
#pragma unroll
        for (int r = 0; r < 4; ++r) { m_run[i][r] = -1e30f; l_run[i][r] = 0.f; }

    const int krow = tid >> 4, kcol = (tid & 15) << 3;  // K: 16 chunks per 128-row
    const int vrow = tid >> 3, vcol = (tid & 7) << 3;   // V: 8 chunks per 64-row
    const bf16* Kg = Kb + (size_t)b * 2048 * 128;
    const bf16* Vg = Vt + (size_t)b * 2048;

    for (int t0 = 0; t0 < 2048; t0 += 64) {
        // stage K/V tile through registers (coalesced bf16x8 global loads)
        bf16x8 kreg[4], vreg[4];
#pragma unroll
        for (int p = 0; p < 4; ++p)
            kreg[p] = *(const bf16x8*)(Kg + (size_t)(t0 + p * 16 + krow) * 128 + kcol);
#pragma unroll
        for (int p = 0; p < 4; ++p)
            vreg[p] = *(const bf16x8*)(Vg + (size_t)(p * 32 + vrow) * 4096 + t0 + vcol);

        __syncthreads();   // barrier 1: prev tile's frag reads done
#pragma unroll
        for (int p = 0; p < 4; ++p)
            *(bf16x8*)(Ks + (p * 16 + krow) * KS_LD + kcol) = kreg[p];
#pragma unroll
        for (int p = 0; p < 4; ++p)
            *(bf16x8*)(Vs + (p * 32 + vrow) * VS_LD + vcol) = vreg[p];
        __syncthreads();   // barrier 2: staging visible

        // ---- S = Q K^T (wave: 32 rows x 64 t) ----
        f32x4 s[2][4];
#pragma unroll
        for (int i = 0; i < 2; ++i)
#pragma unroll
            for (int jt = 0; jt < 4; ++jt) s[i][jt] = f32x4{0.f, 0.f, 0.f, 0.f};
#pragma unroll
        for (int ks = 0; ks < 4; ++ks) {
            bf16x8 kf[4];
#pragma unroll
            for (int jt = 0; jt < 4; ++jt)
                kf[jt] = *(const bf16x8*)(Ks + (jt * 16 + c) * KS_LD + ks * 32 + quad * 8);
#pragma unroll
            for (int i = 0; i < 2; ++i)
#pragma unroll
                for (int jt = 0; jt < 4; ++jt)
                    s[i][jt] = __builtin_amdgcn_mfma_f32_16x16x32_bf16(qf[i][ks], kf[jt], s[i][jt], 0, 0, 0);
        }
#pragma unroll
        for (int i = 0; i < 2; ++i)
#pragma unroll
            for (int jt = 0; jt < 4; ++jt) s[i][jt] *= kScale;

        // ---- online softmax (row stats replicated across the 16 lanes of each quad) ----
        float alpha[2][4];
#pragma unroll
        for (int i = 0; i < 2; ++i)
#pragma unroll
            for (int r = 0; r < 4; ++r) {
                float v = fmaxf(fmaxf(s[i][0][r], s[i][1][r]), fmaxf(s[i][2][r], s[i][3][r]));
                v = fmaxf(v, __shfl_xor(v, 1));
                v = fmaxf(v, __shfl_xor(v, 2));
                v = fmaxf(v, __shfl_xor(v, 4));
                v = fmaxf(v, __shfl_xor(v, 8));
                const float mnew = fmaxf(m_run[i][r], v);
                alpha[i][r] = __expf(m_run[i][r] - mnew);
                m_run[i][r] = mnew;
            }

        float psum[2][4] = {{0.f,0.f,0.f,0.f},{0.f,0.f,0.f,0.f}};
#pragma unroll
        for (int i = 0; i < 2; ++i)
#pragma unroll
            for (int jt = 0; jt < 4; ++jt)
#pragma unroll
                for (int r = 0; r < 4; ++r) {
                    const float p = __expf(s[i][jt][r] - m_run[i][r]);
                    psum[i][r] += p;
                    Ps[(wrow + i * 16 + quad * 4 + r) * PS_LD + jt * 16 + c] = (bf16)p;
                }
#pragma unroll
        for (int i = 0; i < 2; ++i)
#pragma unroll
            for (int r = 0; r < 4; ++r) {
                float v = psum[i][r];
                v += __shfl_xor(v, 1);
                v += __shfl_xor(v, 2);
                v += __shfl_xor(v, 4);
                v += __shfl_xor(v, 8);
                l_run[i][r] = l_run[i][r] * alpha[i][r] + v;
            }

        __syncthreads();   // barrier 3: Ps/Vs ready for PV

        // rescale O by alpha, then O += P V
#pragma unroll
        for (int i = 0; i < 2; ++i)
#pragma unroll
            for (int jd = 0; jd < 8; ++jd)
#pragma unroll
                for (int r = 0; r < 4; ++r) o[i][jd][r] *= alpha[i][r];

#pragma unroll
        for (int kst = 0; kst < 2; ++kst) {
            bf16x8 pa[2], vb[8];
#pragma unroll
            for (int i = 0; i < 2; ++i)
                pa[i] = *(const bf16x8*)(Ps + (wrow + i * 16 + c) * PS_LD + kst * 32 + quad * 8);
#pragma unroll
            for (int jd = 0; jd < 8; ++jd)
                vb[jd] = *(const bf16x8*)(Vs + (jd * 16 + c) * VS_LD + kst * 32 + quad * 8);
#pragma unroll
            for (int i = 0; i < 2; ++i)
#pragma unroll
                for (int jd = 0; jd < 8; ++jd)
                    o[i][jd] = __builtin_amdgcn_mfma_f32_16x16x32_bf16(pa[i], vb[jd], o[i][jd], 0, 0, 0);
        }
    }

    float rinv[2][4];
#pragma unroll
    for (int i = 0; i < 2; ++i)
#pragma unroll
        for (int r = 0; r < 4; ++r) rinv[i][r] = 1.0f / l_run[i][r];

#pragma unroll
    for (int i = 0; i < 2; ++i)
#pragma unroll
        for (int jd = 0; jd < 8; ++jd) {
            const int row = rowbase + wrow + i * 16 + quad * 4;
            const int col = h * 128 + jd * 16 + c;
#pragma unroll
            for (int r = 0; r < 4; ++r)
                AO[(size_t)(row + r) * 2048 + col] = (bf16)(o[i][jd][r] * rinv[i][r]);
        }
}

// ---------------------------------------------------------------------------
extern "C" void kernel_launch(void* const* d_in, const int* in_sizes, int n_in,
                              void* d_out, int out_size, void* d_ws, size_t ws_size,
                              hipStream_t stream)
{
    const float* x  = (const float*)d_in[0];   // [2,2048,2048] f32
    const float* wq = (const float*)d_in[1];   // [2048,2048]   f32
    const float* wk = (const float*)d_in[2];   // [128,2048]    f32
    const float* wv = (const float*)d_in[3];   // [128,2048]    f32
    const float* wo = (const float*)d_in[4];   // [2048,2048]   f32
    float* out = (float*)d_out;                // [2,2048,2048] f32

    // workspace (bf16), 51 MiB total:
    // xb@0(16M) wqb@16M(8M) wkb@24M(.5M) wvb@24.5M(.5M) wob@25M(8M) Qb/AO@33M(16M) Kb@49M(1M) Vt@50M(1M)
    char* ws = (char*)d_ws;
    const size_t MB = 1024 * 1024;
    bf16* xb  = (bf16*)(ws);
    bf16* wqb = (bf16*)(ws + 16 * MB);
    bf16* wkb = (bf16*)(ws + 24 * MB);
    bf16* wvb = (bf16*)(ws + 24 * MB + 512 * 1024);
    bf16* wob = (bf16*)(ws + 25 * MB);
    bf16* Qb  = (bf16*)(ws + 33 * MB);
    bf16* AO  = Qb;                            // alias (safe, see attn note)
    bf16* Kb  = (bf16*)(ws + 49 * MB);
    bf16* Vt  = (bf16*)(ws + 50 * MB);

    cvt_kernel<<<8388608 / 2048, 256, 0, stream>>>(x,  xb);
    cvt_kernel<<<4194304 / 2048, 256, 0, stream>>>(wq, wqb);
    cvt_kernel<<< 262144 / 2048, 256, 0, stream>>>(wk, wkb);
    cvt_kernel<<< 262144 / 2048, 256, 0, stream>>>(wv, wvb);
    cvt_kernel<<<4194304 / 2048, 256, 0, stream>>>(wo, wob);

    qkv_kernel<<<dim3(18, 32), 256, 0, stream>>>(xb, wqb, wkb, wvb, Qb, Kb, Vt);
    attn_kernel<<<dim3(16, 16, 2), 256, 0, stream>>>(Qb, Kb, Vt, AO);
    out_kernel<<<dim3(16, 32), 256, 0, stream>>>(AO, wob, out);
}

// Round 5
// 311.356 us; speedup vs baseline: 1.1961x; 1.1961x over previous
//
#include <hip/hip_runtime.h>

// MQA forward. All reference dtypes float32. Compute in bf16 MFMA, fp32 accum.
// HIDDEN=2048, HEADS=16, HEAD_DIM=128, M=4096 tokens (b=2, s=2048).
// Round 5: GEMMs -> m97 global_load_lds structure; attention computes S^T=K*Q^T
// so the P round-trip is packed b64 writes + b128 reads (no scalar LDS ops);
// single fused cvt kernel.

using bf16   = __bf16;
using bf16x4 = __bf16 __attribute__((ext_vector_type(4)));
using bf16x8 = __bf16 __attribute__((ext_vector_type(8)));
using f32x4  = float  __attribute__((ext_vector_type(4)));

#define GAS __attribute__((address_space(1)))
#define LAS __attribute__((address_space(3)))

// Async global->LDS, 16B per lane. LDS dest is wave-uniform base + lane*16.
__device__ __forceinline__ void load_lds16(const bf16* g, bf16* l) {
    __builtin_amdgcn_global_load_lds((const GAS void*)g, (LAS void*)l, 16, 0, 0);
}

// ---------------------------------------------------------------------------
// Fused f32 -> bf16 conversion of all 5 inputs into contiguous bf16 scratch.
// dst elem offsets: x@0, wq@8388608, wk@12582912, wv@12845056, wo@13107200.
// ---------------------------------------------------------------------------
__global__ __launch_bounds__(256) void cvt_all(
    const float* __restrict__ x,  const float* __restrict__ wq,
    const float* __restrict__ wk, const float* __restrict__ wv,
    const float* __restrict__ wo, bf16* __restrict__ dst)
{
    const size_t i = (size_t)(blockIdx.x * 256 + threadIdx.x) * 8;
    const float* src; size_t off;
    if      (i <  8388608) { src = x;  off = 0; }
    else if (i < 12582912) { src = wq; off = 8388608; }
    else if (i < 12845056) { src = wk; off = 12582912; }
    else if (i < 13107200) { src = wv; off = 12845056; }
    else                   { src = wo; off = 13107200; }
    float4 f0 = *(const float4*)(src + (i - off));
    float4 f1 = *(const float4*)(src + (i - off) + 4);
    bf16x8 v;
    v[0] = (bf16)f0.x; v[1] = (bf16)f0.y; v[2] = (bf16)f0.z; v[3] = (bf16)f0.w;
    v[4] = (bf16)f1.x; v[5] = (bf16)f1.y; v[6] = (bf16)f1.z; v[7] = (bf16)f1.w;
    *(bf16x8*)(dst + i) = v;
}

// ---------------------------------------------------------------------------
// 128x128-tile NT GEMM core: C[M][N] = A[M][2048] * B[N][2048]^T, bf16 inputs.
// m97 structure: BK=32, global_load_lds width-16 staging, 16 MFMA / K-step.
// mode: 0 = bf16 C, 1 = bf16 C transposed (C[n][m]), 2 = f32 C.
// ---------------------------------------------------------------------------
__device__ __forceinline__ void gemm128(
    const bf16* __restrict__ A, const bf16* __restrict__ B, void* __restrict__ Cp,
    int bm, int bn, int ldC, int mode)
{
    __shared__ bf16 As[128 * 32];
    __shared__ bf16 Bs[128 * 32];
    const int K = 2048;

    const int tid  = threadIdx.x;
    const int wave = tid >> 6;
    const int lane = tid & 63;
    const int quad = lane >> 4;
    const int c    = lane & 15;
    const int wm   = (wave >> 1) << 6;
    const int wn   = (wave & 1) << 6;

    // staging map: thread -> (row = tid/4, col8 = (tid%4)*8); LDS elem = tid*8
    const int srow = tid >> 2;
    const int scol = (tid & 3) << 3;
    const bf16* Ag = A + (size_t)(bm + srow) * K + scol;
    const bf16* Bg = B + (size_t)(bn + srow) * K + scol;
    bf16* lA = As + wave * 512;   // wave-uniform LDS base
    bf16* lB = Bs + wave * 512;

    f32x4 acc[4][4];
#pragma unroll
    for (int i = 0; i < 4; ++i)
#pragma unroll
        for (int j = 0; j < 4; ++j)
            acc[i][j] = f32x4{0.f, 0.f, 0.f, 0.f};

    for (int k0 = 0; k0 < K; k0 += 32) {
        load_lds16(Ag + k0,          lA);
        load_lds16(Ag + k0 + 64 * K, lA + 2048);
        load_lds16(Bg + k0,          lB);
        load_lds16(Bg + k0 + 64 * K, lB + 2048);
        __syncthreads();                 // drains vmcnt -> tiles ready

        bf16x8 af[4], bfv[4];
#pragma unroll
        for (int i = 0; i < 4; ++i)
            af[i] = *(const bf16x8*)(As + (wm + i * 16 + c) * 32 + quad * 8);
#pragma unroll
        for (int j = 0; j < 4; ++j)
            bfv[j] = *(const bf16x8*)(Bs + (wn + j * 16 + c) * 32 + quad * 8);
#pragma unroll
        for (int i = 0; i < 4; ++i)
#pragma unroll
            for (int j = 0; j < 4; ++j)
                acc[i][j] = __builtin_amdgcn_mfma_f32_16x16x32_bf16(af[i], bfv[j], acc[i][j], 0, 0, 0);
        __syncthreads();                 // frag reads done before next overwrite
    }

    // C/D layout: col = lane&15, row = quad*4 + reg
    if (mode == 0) {
        bf16* C = (bf16*)Cp;
#pragma unroll
        for (int i = 0; i < 4; ++i) {
            const int m = bm + wm + i * 16 + quad * 4;
#pragma unroll
            for (int j = 0; j < 4; ++j) {
                const int n = bn + wn + j * 16 + c;
#pragma unroll
                for (int r = 0; r < 4; ++r)
                    C[(size_t)(m + r) * ldC + n] = (bf16)acc[i][j][r];
            }
        }
    } else if (mode == 1) {
        bf16* C = (bf16*)Cp;
#pragma unroll
        for (int j = 0; j < 4; ++j) {
            const int n = bn + wn + j * 16 + c;
#pragma unroll
            for (int i = 0; i < 4; ++i) {
                const int m = bm + wm + i * 16 + quad * 4;
                bf16x4 v;
#pragma unroll
                for (int r = 0; r < 4; ++r) v[r] = (bf16)acc[i][j][r];
                *(bf16x4*)(C + (size_t)n * ldC + m) = v;
            }
        }
    } else {
        float* C = (float*)Cp;
#pragma unroll
        for (int i = 0; i < 4; ++i) {
            const int m = bm + wm + i * 16 + quad * 4;
#pragma unroll
            for (int j = 0; j < 4; ++j) {
                const int n = bn + wn + j * 16 + c;
#pragma unroll
                for (int r = 0; r < 4; ++r)
                    C[(size_t)(m + r) * ldC + n] = acc[i][j][r];
            }
        }
    }
}

// bx 0..15: Q = x @ w_q^T (cols bx*128); bx==16: K = x @ w_k^T; bx==17: V^T (transposed)
__global__ __launch_bounds__(256) void qkv_kernel(
    const bf16* __restrict__ x,  const bf16* __restrict__ wq,
    const bf16* __restrict__ wk, const bf16* __restrict__ wv,
    bf16* __restrict__ Qb, bf16* __restrict__ Kb, bf16* __restrict__ Vt)
{
    const int bx = blockIdx.x;
    const int bm = blockIdx.y << 7;
    const bf16* B; bf16* C; int ldC, bn, mode;
    if (bx < 16)       { B = wq; C = Qb; ldC = 2048; bn = bx << 7; mode = 0; }
    else if (bx == 16) { B = wk; C = Kb; ldC = 128;  bn = 0;       mode = 0; }
    else               { B = wv; C = Vt; ldC = 4096; bn = 0;       mode = 1; }
    gemm128(x, B, C, bm, bn, ldC, mode);
}

__global__ __launch_bounds__(256) void out_kernel(
    const bf16* __restrict__ AO, const bf16* __restrict__ wo, float* __restrict__ out)
{
    gemm128(AO, wo, out, blockIdx.y << 7, blockIdx.x << 7, 2048, 2);
}

// ---------------------------------------------------------------------------
// Flash attention, S^T formulation. One block per (q-tile 128, head, batch).
// t-tile 64. Wave w owns qrows w*32..w*32+31.
//   S^T = K * Q^T  -> C/D lane (q,c) holds S^T[t = mt*16+q*4+r][qrow = nq*16+c]:
//     4 consecutive t per lane -> packed bf16x4 write into Ps[qrow][t].
//   O^T = V^T * P^T -> pa/vb are plain b128 A/B-frag reads; epilogue packed 8B.
// Softmax stats per qrow=c: reduce across quads only (shfl_xor 16,32).
// Ps rows are wave-private -> wave-local s_waitcnt instead of a 3rd barrier.
// AO may alias Qb: block reads only its own (rows, head) slice of Q at start,
// writes exactly that slice of AO at end.
// ---------------------------------------------------------------------------
#define KS_LD 136   // 128 + 8 pad (row stride 272 B: 16B-aligned, 2-way banks = free)
#define VS_LD 72    // 64 + 8 pad (144 B rows)
#define PS_LD 72

__global__ __launch_bounds__(256, 2) void attn_kernel(
    const bf16* __restrict__ Qb, const bf16* __restrict__ Kb,
    const bf16* __restrict__ Vt, bf16* __restrict__ AO)
{
    __shared__ bf16 Ks[64 * KS_LD];   // [t][d]
    __shared__ bf16 Vs[128 * VS_LD];  // [d][t]
    __shared__ bf16 Ps[128 * PS_LD];  // [qrow][t]

    const float kScale = 0.08838834764831845f;  // 1/sqrt(128)
    const int tid  = threadIdx.x;
    const int lane = tid & 63;
    const int wave = tid >> 6;
    const int q    = lane >> 4;       // quad
    const int c    = lane & 15;
    const int qt = blockIdx.x, h = blockIdx.y, b = blockIdx.z;
    const int rowbase = b * 2048 + qt * 128;
    const int wrow = wave * 32;

    // Q as B-operand frags: lane holds Q[qrow = wrow+nq*16+c][d = ks*32+q*8 ..+7]
    bf16x8 qf[2][4];
#pragma unroll
    for (int nq = 0; nq < 2; ++nq)
#pragma unroll
        for (int ks = 0; ks < 4; ++ks)
            qf[nq][ks] = *(const bf16x8*)(Qb + (size_t)(rowbase + wrow + nq * 16 + c) * 2048
                                             + h * 128 + ks * 32 + q * 8);

    f32x4 o[8][2];   // O^T accum: [d-tile][qrow-tile], lane: d = mtv*16+q*4+r, qrow = nq*16+c
#pragma unroll
    for (int mtv = 0; mtv < 8; ++mtv)
#pragma unroll
        for (int nq = 0; nq < 2; ++nq) o[mtv][nq] = f32x4{0.f, 0.f, 0.f, 0.f};

    float m_run[2] = {-1e30f, -1e30f}, l_run[2] = {0.f, 0.f};

    const int krow = tid >> 4, kcol = (tid & 15) << 3;  // K staging: 16 chunks / 128-row
    const int vrow = tid >> 3, vcol = (tid & 7) << 3;   // V staging: 8 chunks / 64-row
    const bf16* Kg = Kb + (size_t)b * 2048 * 128;
    const bf16* Vg = Vt + (size_t)b * 2048;

    for (int t0 = 0; t0 < 2048; t0 += 64) {
        // prefetch K/V tile into registers (overlaps with previous tile's math)
        bf16x8 kreg[4], vreg[4];
#pragma unroll
        for (int p = 0; p < 4; ++p)
            kreg[p] = *(const bf16x8*)(Kg + (size_t)(t0 + p * 16 + krow) * 128 + kcol);
#pragma unroll
        for (int p = 0; p < 4; ++p)
            vreg[p] = *(const bf16x8*)(Vg + (size_t)(p * 32 + vrow) * 4096 + t0 + vcol);

        __syncthreads();   // barrier 1: prev tile's frag reads done
#pragma unroll
        for (int p = 0; p < 4; ++p)
            *(bf16x8*)(Ks + (p * 16 + krow) * KS_LD + kcol) = kreg[p];
#pragma unroll
        for (int p = 0; p < 4; ++p)
            *(bf16x8*)(Vs + (p * 32 + vrow) * VS_LD + vcol) = vreg[p];
        __syncthreads();   // barrier 2: staging visible

        // ---- S^T = K Q^T : s[mt][nq], lane holds S^T[mt*16+q*4+r][nq*16+c] ----
        f32x4 s[4][2];
#pragma unroll
        for (int mt = 0; mt < 4; ++mt)
#pragma unroll
            for (int nq = 0; nq < 2; ++nq) s[mt][nq] = f32x4{0.f, 0.f, 0.f, 0.f};
#pragma unroll
        for (int ks = 0; ks < 4; ++ks) {
            bf16x8 kf[4];
#pragma unroll
            for (int mt = 0; mt < 4; ++mt)
                kf[mt] = *(const bf16x8*)(Ks + (mt * 16 + c) * KS_LD + ks * 32 + q * 8);
#pragma unroll
            for (int mt = 0; mt < 4; ++mt)
#pragma unroll
                for (int nq = 0; nq < 2; ++nq)
                    s[mt][nq] = __builtin_amdgcn_mfma_f32_16x16x32_bf16(kf[mt], qf[nq][ks], s[mt][nq], 0, 0, 0);
        }
#pragma unroll
        for (int mt = 0; mt < 4; ++mt)
#pragma unroll
            for (int nq = 0; nq < 2; ++nq) s[mt][nq] *= kScale;

        // ---- online softmax; stats per qrow = nq*16+c (reduce across quads) ----
        float alpha[2];
#pragma unroll
        for (int nq = 0; nq < 2; ++nq) {
            float v = -1e30f;
#pragma unroll
            for (int mt = 0; mt < 4; ++mt)
#pragma unroll
                for (int r = 0; r < 4; ++r) v = fmaxf(v, s[mt][nq][r]);
            v = fmaxf(v, __shfl_xor(v, 16));
            v = fmaxf(v, __shfl_xor(v, 32));
            const float mnew = fmaxf(m_run[nq], v);
            alpha[nq] = __expf(m_run[nq] - mnew);
            m_run[nq] = mnew;
        }

        float psum[2] = {0.f, 0.f};
#pragma unroll
        for (int mt = 0; mt < 4; ++mt)
#pragma unroll
            for (int nq = 0; nq < 2; ++nq) {
                bf16x4 pv;
#pragma unroll
                for (int r = 0; r < 4; ++r) {
                    const float p = __expf(s[mt][nq][r] - m_run[nq]);
                    psum[nq] += p;
                    pv[r] = (bf16)p;
                }
                *(bf16x4*)(Ps + (wrow + nq * 16 + c) * PS_LD + mt * 16 + q * 4) = pv;
            }
#pragma unroll
        for (int nq = 0; nq < 2; ++nq) {
            float v = psum[nq];
            v += __shfl_xor(v, 16);
            v += __shfl_xor(v, 32);
            l_run[nq] = l_run[nq] * alpha[nq] + v;
        }

        // rescale O^T by alpha (uniform per qrow-column)
#pragma unroll
        for (int mtv = 0; mtv < 8; ++mtv)
#pragma unroll
            for (int nq = 0; nq < 2; ++nq)
#pragma unroll
                for (int r = 0; r < 4; ++r) o[mtv][nq][r] *= alpha[nq];

        // Ps rows are wave-private: wave-local drain of LDS writes, no barrier
        asm volatile("s_waitcnt lgkmcnt(0)" ::: "memory");

        // ---- O^T += V^T P^T ----
#pragma unroll
        for (int kst = 0; kst < 2; ++kst) {
            bf16x8 pa[2], vb[8];
#pragma unroll
            for (int nq = 0; nq < 2; ++nq)
                pa[nq] = *(const bf16x8*)(Ps + (wrow + nq * 16 + c) * PS_LD + kst * 32 + q * 8);
#pragma unroll
            for (int mtv = 0; mtv < 8; ++mtv)
                vb[mtv] = *(const bf16x8*)(Vs + (mtv * 16 + c) * VS_LD + kst * 32 + q * 8);
#pragma unroll
            for (int mtv = 0; mtv < 8; ++mtv)
#pragma unroll
                for (int nq = 0; nq < 2; ++nq)
                    o[mtv][nq] = __builtin_amdgcn_mfma_f32_16x16x32_bf16(vb[mtv], pa[nq], o[mtv][nq], 0, 0, 0);
        }
    }

    // epilogue: AO[qrow][h*128 + d], 4 consecutive d per (mtv) -> packed 8B stores
#pragma unroll
    for (int nq = 0; nq < 2; ++nq) {
        const float rinv = 1.0f / l_run[nq];
        const size_t row = (size_t)(rowbase + wrow + nq * 16 + c) * 2048 + h * 128;
#pragma unroll
        for (int mtv = 0; mtv < 8; ++mtv) {
            bf16x4 v;
#pragma unroll
            for (int r = 0; r < 4; ++r) v[r] = (bf16)(o[mtv][nq][r] * rinv);
            *(bf16x4*)(AO + row + mtv * 16 + q * 4) = v;
        }
    }
}

// ---------------------------------------------------------------------------
extern "C" void kernel_launch(void* const* d_in, const int* in_sizes, int n_in,
                              void* d_out, int out_size, void* d_ws, size_t ws_size,
                              hipStream_t stream)
{
    const float* x  = (const float*)d_in[0];   // [2,2048,2048] f32
    const float* wq = (const float*)d_in[1];   // [2048,2048]   f32
    const float* wk = (const float*)d_in[2];   // [128,2048]    f32
    const float* wv = (const float*)d_in[3];   // [128,2048]    f32
    const float* wo = (const float*)d_in[4];   // [2048,2048]   f32
    float* out = (float*)d_out;                // [2,2048,2048] f32

    // workspace (bf16), 51 MiB total:
    // xb@0(16M) wqb@16M(8M) wkb@24M(.5M) wvb@24.5M(.5M) wob@25M(8M) Qb/AO@33M(16M) Kb@49M(1M) Vt@50M(1M)
    char* ws = (char*)d_ws;
    const size_t MB = 1024 * 1024;
    bf16* xb  = (bf16*)(ws);
    bf16* wqb = (bf16*)(ws + 16 * MB);
    bf16* wkb = (bf16*)(ws + 24 * MB);
    bf16* wvb = (bf16*)(ws + 24 * MB + 512 * 1024);
    bf16* wob = (bf16*)(ws + 25 * MB);
    bf16* Qb  = (bf16*)(ws + 33 * MB);
    bf16* AO  = Qb;                            // alias (safe, see attn note)
    bf16* Kb  = (bf16*)(ws + 49 * MB);
    bf16* Vt  = (bf16*)(ws + 50 * MB);

    cvt_all<<<17301504 / 2048, 256, 0, stream>>>(x, wq, wk, wv, wo, xb);
    qkv_kernel<<<dim3(18, 32), 256, 0, stream>>>(xb, wqb, wkb, wvb, Qb, Kb, Vt);
    attn_kernel<<<dim3(16, 16, 2), 256, 0, stream>>>(Qb, Kb, Vt, AO);
    out_kernel<<<dim3(16, 32), 256, 0, stream>>>(AO, wob, out);
}